// Round 8
// baseline (268.804 us; speedup 1.0000x reference)
//
#include <hip/hip_runtime.h>
#include <hip/hip_bf16.h>
#include <math.h>

constexpr int BB = 4;     // batch
constexpr int TT = 2048;  // sequence
constexpr int CC = 768;   // channels
constexpr int HH = 64;    // head dim
constexpr int NSPLIT = 8; // attention s-splits

// Softmax is computed in base-2: q carries 0.125*log2(e), exp -> exp2.
#define QSCALE 0.1803368801111204f   // 0.125 * log2(e)

typedef __attribute__((ext_vector_type(8))) short bf16x8;   // 8 bf16 = 4 VGPR
typedef __attribute__((ext_vector_type(4))) float f32x4;    // MFMA C/D

__device__ inline ushort f2bf(float f) {   // fp32 -> bf16 RNE (scalar)
    uint u = __float_as_uint(f);
    u += 0x7fffu + ((u >> 16) & 1u);
    return (ushort)(u >> 16);
}

__device__ inline float fexp2(float x) { return __builtin_amdgcn_exp2f(x); }

__device__ inline bf16x8 cvt8(const float4 a, const float4 b) {  // packed cvt
    union { bf16x8 v; __hip_bfloat162 h[4]; } u;
    u.h[0] = __float22bfloat162_rn(make_float2(a.x, a.y));
    u.h[1] = __float22bfloat162_rn(make_float2(a.z, a.w));
    u.h[2] = __float22bfloat162_rn(make_float2(b.x, b.y));
    u.h[3] = __float22bfloat162_rn(make_float2(b.z, b.w));
    return u.v;
}

// ---------------------------------------------------------------------------
// prep_w: W[768][64] fp32 -> Wt[mat][n][768] bf16 (transposed, k-contiguous)
// ---------------------------------------------------------------------------
__global__ __launch_bounds__(256) void prep_w(const float* __restrict__ Wq,
                                              const float* __restrict__ Wk,
                                              const float* __restrict__ Wv,
                                              ushort* __restrict__ Wt) {
    const int k0  = blockIdx.x * 64;
    const int mat = blockIdx.y;
    const float* W = (mat == 0) ? Wq : (mat == 1) ? Wk : Wv;
    __shared__ ushort tile[64 * 66];
    const int tid = threadIdx.x;

    for (int i = tid; i < 1024; i += 256) {
        int kk = i >> 4, c = i & 15;
        float4 f = ((const float4*)W)[(k0 + kk) * 16 + c];
        ushort* d = &tile[kk * 66 + c * 4];
        d[0] = f2bf(f.x); d[1] = f2bf(f.y); d[2] = f2bf(f.z); d[3] = f2bf(f.w);
    }
    __syncthreads();
    for (int i = tid; i < 512; i += 256) {
        int n = i >> 3, c8 = i & 7;
        bf16x8 v;
        #pragma unroll
        for (int j = 0; j < 8; ++j)
            ((ushort*)&v)[j] = tile[(c8 * 8 + j) * 66 + n];
        *(bf16x8*)&Wt[(size_t)(mat * 64 + n) * CC + k0 + c8 * 8] = v;
    }
}

// ---------------------------------------------------------------------------
// qkv_mfma: 16 rows x 192 cols per block, 4 waves col-split, explicit
// 4-deep register prefetch pipeline on x and Wt (~20 loads in flight/wave).
// q pre-scaled by 0.125*log2e (base-2 softmax downstream).
// ---------------------------------------------------------------------------
__global__ __launch_bounds__(256) void qkv_mfma(const float* __restrict__ x,
                                                const ushort* __restrict__ Wt,
                                                ushort* __restrict__ qg,
                                                ushort* __restrict__ kg,
                                                ushort* __restrict__ vtg) {
    __shared__ ushort vts[64 * 24];      // [h][t-local 0..15], stride 24
    const int tid  = threadIdx.x;
    const int row0 = blockIdx.x * 16;
    const int lane = tid & 63, w = tid >> 6;
    const int l15  = lane & 15, quad = lane >> 4;
    const int cg   = w * 48;             // this wave's first output col

    f32x4 acc[3];
    #pragma unroll
    for (int i = 0; i < 3; ++i) acc[i] = (f32x4){0.f, 0.f, 0.f, 0.f};

    const float*  xrow  = x + (size_t)(row0 + l15) * CC;
    const ushort* wbase = Wt + (size_t)(cg + l15) * CC + quad * 8;

    float4 xb[4][2];
    bf16x8 wb[4][3];
    #pragma unroll
    for (int i = 0; i < 4; ++i) {        // prime the pipeline: kc = 0..3
        const float4* xp = (const float4*)(xrow + i * 32) + quad * 2;
        xb[i][0] = xp[0];
        xb[i][1] = xp[1];
        #pragma unroll
        for (int nt = 0; nt < 3; ++nt)
            wb[i][nt] = *(const bf16x8*)(wbase + (size_t)nt * 16 * CC + i * 32);
    }

    #pragma unroll
    for (int kc = 0; kc < 24; ++kc) {
        const int cur = kc & 3;
        bf16x8 a  = cvt8(xb[cur][0], xb[cur][1]);
        bf16x8 w0 = wb[cur][0], w1 = wb[cur][1], w2 = wb[cur][2];
        const int nx = kc + 4;
        if (nx < 24) {                   // refill slot: loads issue before MFMAs
            const float4* xp = (const float4*)(xrow + nx * 32) + quad * 2;
            xb[cur][0] = xp[0];
            xb[cur][1] = xp[1];
            #pragma unroll
            for (int nt = 0; nt < 3; ++nt)
                wb[cur][nt] = *(const bf16x8*)(wbase + (size_t)nt * 16 * CC + nx * 32);
        }
        acc[0] = __builtin_amdgcn_mfma_f32_16x16x32_bf16(a, w0, acc[0], 0, 0, 0);
        acc[1] = __builtin_amdgcn_mfma_f32_16x16x32_bf16(a, w1, acc[1], 0, 0, 0);
        acc[2] = __builtin_amdgcn_mfma_f32_16x16x32_bf16(a, w2, acc[2], 0, 0, 0);
    }

    // epilogue: C layout row = quad*4+r (16-row tile), col = l15 (+16*nt)
    #pragma unroll
    for (int nt = 0; nt < 3; ++nt) {
        int n = cg + nt * 16 + l15;
        #pragma unroll
        for (int r = 0; r < 4; ++r) {
            int row = row0 + quad * 4 + r;
            float vacc = acc[nt][r];
            if (n < 64)       qg[(size_t)row * HH + n] = f2bf(vacc * QSCALE);
            else if (n < 128) kg[(size_t)row * HH + (n - 64)] = f2bf(vacc);
            else              vts[(n - 128) * 24 + (quad * 4 + r)] = f2bf(vacc);
        }
    }
    __syncthreads();
    if (tid < 128) {   // cooperative write vt[b][h][t0..t0+15]
        int h = tid >> 1, p = tid & 1;
        int b = row0 >> 11, tl = row0 & 2047;
        bf16x8 v = *(const bf16x8*)&vts[h * 24 + p * 8];
        *(bf16x8*)&vtg[(size_t)b * (HH * TT) + (size_t)h * TT + tl + p * 8] = v;
    }
}

// ---------------------------------------------------------------------------
// attn_fused: 32-query tile (2 waves) x 8-way s-split + last-block merge.
// Split phase identical to R7 (K prefetch, V early-issue, base-2 softmax).
// After partial writes: __threadfence (cross-XCD wb+inv), atomic ticket per
// (b,qt) group; the 8th arriving block merges all partials and writes out.
// Output is independent of arrival order -> replay-deterministic.
// ---------------------------------------------------------------------------
__global__ __launch_bounds__(128) void attn_fused(const ushort* __restrict__ qg,
                                                  const ushort* __restrict__ kg,
                                                  const ushort* __restrict__ vtg,
                                                  float* __restrict__ Op,
                                                  float* __restrict__ ml,
                                                  int* __restrict__ cnt,
                                                  float* __restrict__ out) {
    const int qt2 = blockIdx.x, b = blockIdx.y, split = blockIdx.z;
    const int tid  = threadIdx.x;
    const int lane = tid & 63, w = tid >> 6;
    const int l15  = lane & 15, quad = lane >> 4;
    const int t0   = qt2 * 32;
    const int grp  = b * 64 + qt2;
    const int pidx = (grp << 3) + split;

    const int ntile = (qt2 >> 1) + 1;     // 64-wide s-tiles covering s <= t0+31
    const int lo = (ntile * split) >> 3;
    const int hi = (ntile * (split + 1)) >> 3;

    __shared__ ushort Ps[2][16 * 72];
    __shared__ int sOld;

    if (lo >= hi) {   // empty split: zero partials
        float4 z = (float4){0.f, 0.f, 0.f, 0.f};
        float4* op4 = (float4*)(Op + (size_t)pidx * 2048);
        #pragma unroll
        for (int j = 0; j < 4; ++j) op4[tid * 4 + j] = z;
        if (tid < 32) {
            ml[pidx * 64 + tid]      = -1e30f;
            ml[pidx * 64 + 32 + tid] = 0.f;
        }
    } else {
        // Q fragments direct from global (q pre-scaled by 0.125*log2e)
        const ushort* qp = &qg[(size_t)(b * TT + t0 + w * 16 + l15) * HH + quad * 8];
        bf16x8 qa0 = *(const bf16x8*)qp;
        bf16x8 qa1 = *(const bf16x8*)(qp + 32);

        const ushort* kbb = &kg[(size_t)(b * TT + l15) * HH + quad * 8];
        const ushort* vbb = &vtg[(size_t)b * (HH * TT) + (size_t)l15 * TT + quad * 8];

        f32x4 po[4];
        #pragma unroll
        for (int i = 0; i < 4; ++i) po[i] = (f32x4){0.f, 0.f, 0.f, 0.f};
        float mrun[4] = {-1e30f, -1e30f, -1e30f, -1e30f};
        float lrun[4] = {0.f, 0.f, 0.f, 0.f};

        bf16x8 kb[8], vb[8];
        #pragma unroll
        for (int nt = 0; nt < 4; ++nt) {     // prime K for st = lo
            const ushort* kp = kbb + (size_t)(lo * 64 + nt * 16) * HH;
            kb[2 * nt]     = *(const bf16x8*)kp;
            kb[2 * nt + 1] = *(const bf16x8*)(kp + 32);
        }

        for (int st = lo; st < hi; ++st) {
            // S = Q K^T (uses prefetched kb)
            f32x4 sf[4];
            #pragma unroll
            for (int nt = 0; nt < 4; ++nt) {
                f32x4 z = (f32x4){0.f, 0.f, 0.f, 0.f};
                z = __builtin_amdgcn_mfma_f32_16x16x32_bf16(qa0, kb[2 * nt], z, 0, 0, 0);
                sf[nt] = __builtin_amdgcn_mfma_f32_16x16x32_bf16(qa1, kb[2 * nt + 1], z, 0, 0, 0);
            }
            // prefetch next K (latency hidden under softmax + PV)
            if (st + 1 < hi) {
                #pragma unroll
                for (int nt = 0; nt < 4; ++nt) {
                    const ushort* kp = kbb + (size_t)((st + 1) * 64 + nt * 16) * HH;
                    kb[2 * nt]     = *(const bf16x8*)kp;
                    kb[2 * nt + 1] = *(const bf16x8*)(kp + 32);
                }
            }
            // issue V loads for this step (consumed after softmax + P transpose)
            #pragma unroll
            for (int jj = 0; jj < 4; ++jj) {
                const ushort* vp = vbb + (size_t)(jj * 16) * TT + st * 64;
                vb[2 * jj]     = *(const bf16x8*)vp;
                vb[2 * jj + 1] = *(const bf16x8*)(vp + 32);
            }

            // causal mask (diagonal tile in last split) + online softmax
            float p[4][4];
            float rm[4] = {-1e30f, -1e30f, -1e30f, -1e30f};
            if (st == ntile - 1) {
                #pragma unroll
                for (int nt = 0; nt < 4; ++nt) {
                    int s_abs = st * 64 + nt * 16 + l15;
                    #pragma unroll
                    for (int r = 0; r < 4; ++r) {
                        int t_abs = t0 + w * 16 + quad * 4 + r;
                        float v = (s_abs > t_abs) ? -1e30f : sf[nt][r];
                        p[nt][r] = v;
                        rm[r] = fmaxf(rm[r], v);
                    }
                }
            } else {
                #pragma unroll
                for (int nt = 0; nt < 4; ++nt)
                    #pragma unroll
                    for (int r = 0; r < 4; ++r) {
                        p[nt][r] = sf[nt][r];
                        rm[r] = fmaxf(rm[r], sf[nt][r]);
                    }
            }
            float alpha[4], rs[4] = {0.f, 0.f, 0.f, 0.f};
            #pragma unroll
            for (int r = 0; r < 4; ++r) {
                float v = rm[r];
                v = fmaxf(v, __shfl_xor(v, 1, 64));
                v = fmaxf(v, __shfl_xor(v, 2, 64));
                v = fmaxf(v, __shfl_xor(v, 4, 64));
                v = fmaxf(v, __shfl_xor(v, 8, 64));
                float mnew = fmaxf(mrun[r], v);
                alpha[r] = fexp2(mrun[r] - mnew);
                mrun[r] = mnew;
            }
            #pragma unroll
            for (int nt = 0; nt < 4; ++nt)
                #pragma unroll
                for (int r = 0; r < 4; ++r) {
                    float e = fexp2(p[nt][r] - mrun[r]);
                    p[nt][r] = e;
                    rs[r] += e;
                }
            #pragma unroll
            for (int r = 0; r < 4; ++r) {
                float v = rs[r];
                v += __shfl_xor(v, 1, 64);
                v += __shfl_xor(v, 2, 64);
                v += __shfl_xor(v, 4, 64);
                v += __shfl_xor(v, 8, 64);
                lrun[r] = lrun[r] * alpha[r] + v;
            }
            #pragma unroll
            for (int jj = 0; jj < 4; ++jj)
                #pragma unroll
                for (int r = 0; r < 4; ++r)
                    po[jj][r] *= alpha[r];

            // P: C-layout regs -> per-wave LDS -> A-layout frags (no barrier)
            #pragma unroll
            for (int nt = 0; nt < 4; ++nt)
                #pragma unroll
                for (int r = 0; r < 4; ++r)
                    Ps[w][(quad * 4 + r) * 72 + nt * 16 + l15] = f2bf(p[nt][r]);
            bf16x8 pa0 = *(const bf16x8*)&Ps[w][l15 * 72 + quad * 8];
            bf16x8 pa1 = *(const bf16x8*)&Ps[w][l15 * 72 + 32 + quad * 8];

            // O += P V (uses vb issued before softmax)
            #pragma unroll
            for (int jj = 0; jj < 4; ++jj) {
                po[jj] = __builtin_amdgcn_mfma_f32_16x16x32_bf16(pa0, vb[2 * jj], po[jj], 0, 0, 0);
                po[jj] = __builtin_amdgcn_mfma_f32_16x16x32_bf16(pa1, vb[2 * jj + 1], po[jj], 0, 0, 0);
            }
        }

        // write partials: unnormalized O + per-row m, l
        #pragma unroll
        for (int jj = 0; jj < 4; ++jj)
            #pragma unroll
            for (int r = 0; r < 4; ++r)
                Op[(size_t)pidx * 2048 + (w * 16 + quad * 4 + r) * 64 + jj * 16 + l15] =
                    po[jj][r];
        if (l15 == 0) {
            #pragma unroll
            for (int r = 0; r < 4; ++r) {
                int row = w * 16 + quad * 4 + r;
                ml[pidx * 64 + row]      = mrun[r];
                ml[pidx * 64 + 32 + row] = lrun[r];
            }
        }
    }

    // ---- arrive: device fence (cross-XCD wb+inv) + ticket ----
    __threadfence();
    if (tid == 0) sOld = atomicAdd(&cnt[grp], 1);
    __syncthreads();
    if (sOld != NSPLIT - 1) return;
    __threadfence();   // acquire side before reading other blocks' partials

    // ---- merge phase: 32 rows x 64 h for this (b, qt2) group ----
    const int pbase = grp << 3;
    for (int rr = w; rr < 32; rr += 2) {      // wave per row
        float m[NSPLIT], l[NSPLIT];
        #pragma unroll
        for (int i = 0; i < NSPLIT; ++i) {
            m[i] = ml[(pbase + i) * 64 + rr];
            l[i] = ml[(pbase + i) * 64 + 32 + rr];
        }
        float M = -1e30f;
        #pragma unroll
        for (int i = 0; i < NSPLIT; ++i) M = fmaxf(M, m[i]);
        float wgt[NSPLIT], L = 0.f;
        #pragma unroll
        for (int i = 0; i < NSPLIT; ++i) {
            wgt[i] = fexp2(m[i] - M);
            L += wgt[i] * l[i];
        }
        float acc = 0.f;
        #pragma unroll
        for (int i = 0; i < NSPLIT; ++i)
            acc += wgt[i] * Op[(size_t)(pbase + i) * 2048 + rr * 64 + lane];
        out[(size_t)(b * TT + t0 + rr) * HH + lane] = acc / L;
    }
}

// ---------------------------------------------------------------------------
extern "C" void kernel_launch(void* const* d_in, const int* in_sizes, int n_in,
                              void* d_out, int out_size, void* d_ws, size_t ws_size,
                              hipStream_t stream)
{
    const float* x  = (const float*)d_in[0];
    const float* Wq = (const float*)d_in[1];
    const float* Wk = (const float*)d_in[2];
    const float* Wv = (const float*)d_in[3];
    float* out = (float*)d_out;

    // ws layout: qg 1MB | kg 1MB | vtg 1MB | Wt 288KB | Op 16.8MB | ml 512KB | cnt 1KB
    ushort* qg  = (ushort*)d_ws;
    ushort* kg  = qg  + (size_t)BB * TT * HH;
    ushort* vtg = kg  + (size_t)BB * TT * HH;
    ushort* Wt  = vtg + (size_t)BB * TT * HH;
    float*  Op  = (float*)(Wt + (size_t)3 * HH * CC);
    float*  ml  = Op + (size_t)2048 * 2048;
    int*    cnt = (int*)(ml + (size_t)2048 * 64);

    hipMemsetAsync(cnt, 0, 256 * sizeof(int), stream);
    prep_w    <<<dim3(12, 3),           dim3(256), 0, stream>>>(Wq, Wk, Wv, Wt);
    qkv_mfma  <<<dim3((BB * TT) / 16),  dim3(256), 0, stream>>>(x, Wt, qg, kg, vtg);
    attn_fused<<<dim3(64, BB, NSPLIT),  dim3(128), 0, stream>>>(qg, kg, vtg, Op, ml, cnt, out);
}

// Round 9
// 118.826 us; speedup vs baseline: 2.2622x; 2.2622x over previous
//
#include <hip/hip_runtime.h>
#include <hip/hip_bf16.h>
#include <math.h>

constexpr int BB = 4;     // batch
constexpr int TT = 2048;  // sequence
constexpr int CC = 768;   // channels
constexpr int HH = 64;    // head dim
constexpr int NSPLIT = 8; // attention s-splits

// Softmax is computed in base-2: q carries 0.125*log2(e), exp -> exp2.
#define QSCALE 0.1803368801111204f   // 0.125 * log2(e)

typedef __attribute__((ext_vector_type(8))) short bf16x8;   // 8 bf16 = 4 VGPR
typedef __attribute__((ext_vector_type(4))) float f32x4;    // MFMA C/D

__device__ inline ushort f2bf(float f) {   // fp32 -> bf16 RNE (scalar)
    uint u = __float_as_uint(f);
    u += 0x7fffu + ((u >> 16) & 1u);
    return (ushort)(u >> 16);
}

__device__ inline float fexp2(float x) { return __builtin_amdgcn_exp2f(x); }

__device__ inline bf16x8 cvt8(const float4 a, const float4 b) {  // packed cvt
    union { bf16x8 v; __hip_bfloat162 h[4]; } u;
    u.h[0] = __float22bfloat162_rn(make_float2(a.x, a.y));
    u.h[1] = __float22bfloat162_rn(make_float2(a.z, a.w));
    u.h[2] = __float22bfloat162_rn(make_float2(b.x, b.y));
    u.h[3] = __float22bfloat162_rn(make_float2(b.z, b.w));
    return u.v;
}

// ---------------------------------------------------------------------------
// prep_w: W[768][64] fp32 -> Wt[mat][n][768] bf16 (transposed, k-contiguous)
// ---------------------------------------------------------------------------
__global__ __launch_bounds__(256) void prep_w(const float* __restrict__ Wq,
                                              const float* __restrict__ Wk,
                                              const float* __restrict__ Wv,
                                              ushort* __restrict__ Wt) {
    const int k0  = blockIdx.x * 64;
    const int mat = blockIdx.y;
    const float* W = (mat == 0) ? Wq : (mat == 1) ? Wk : Wv;
    __shared__ ushort tile[64 * 66];
    const int tid = threadIdx.x;

    for (int i = tid; i < 1024; i += 256) {
        int kk = i >> 4, c = i & 15;
        float4 f = ((const float4*)W)[(k0 + kk) * 16 + c];
        ushort* d = &tile[kk * 66 + c * 4];
        d[0] = f2bf(f.x); d[1] = f2bf(f.y); d[2] = f2bf(f.z); d[3] = f2bf(f.w);
    }
    __syncthreads();
    for (int i = tid; i < 512; i += 256) {
        int n = i >> 3, c8 = i & 7;
        bf16x8 v;
        #pragma unroll
        for (int j = 0; j < 8; ++j)
            ((ushort*)&v)[j] = tile[(c8 * 8 + j) * 66 + n];
        *(bf16x8*)&Wt[(size_t)(mat * 64 + n) * CC + k0 + c8 * 8] = v;
    }
}

// ---------------------------------------------------------------------------
// qkv_mfma v5 (m97-style): 32 rows x 192 cols per block, 256 blocks.
// BK=64 double-buffered LDS; coalesced cooperative staging (x: 32B/lane
// contiguous row-chunks; Wt: 16B chunks); register prefetch of chunk kc+1
// issued before computing chunk kc; ONE barrier per chunk (alternating
// buffers: writes target the buffer last read before the previous barrier).
// Fragments via ds_read_b128 (2-way bank alias = free).
// ---------------------------------------------------------------------------
__global__ __launch_bounds__(256) void qkv_mfma(const float* __restrict__ x,
                                                const ushort* __restrict__ Wt,
                                                ushort* __restrict__ qg,
                                                ushort* __restrict__ kg,
                                                ushort* __restrict__ vtg) {
    __shared__ ushort xs[2][32 * 72];
    __shared__ ushort ws[2][192 * 72];
    __shared__ ushort vts[64 * 40];      // [h][t-local 0..31]
    const int tid  = threadIdx.x;
    const int row0 = blockIdx.x * 32;
    const int lane = tid & 63, w = tid >> 6;
    const int l15  = lane & 15, quad = lane >> 4;
    const int m0   = (w & 1) * 16;       // row sub-tile
    const int cg   = (w >> 1) * 96;      // col half

    f32x4 acc[6];
    #pragma unroll
    for (int i = 0; i < 6; ++i) acc[i] = (f32x4){0.f, 0.f, 0.f, 0.f};

    // staging assignments
    const int ar = tid >> 3, ac = tid & 7;          // x: row 0..31, 8-float col chunk
    const float* xg = x + (size_t)(row0 + ar) * CC + ac * 8;

    // prologue: stage chunk 0 into buffer 0
    {
        const float4* xp = (const float4*)xg;
        *(bf16x8*)&xs[0][ar * 72 + ac * 8] = cvt8(xp[0], xp[1]);
        #pragma unroll
        for (int j = 0; j < 6; ++j) {
            int c = tid + j * 256;                   // 1536 16B-chunks
            int rw = c >> 3, cc = c & 7;
            *(bf16x8*)&ws[0][rw * 72 + cc * 8] =
                *(const bf16x8*)&Wt[(size_t)rw * CC + cc * 8];
        }
    }
    __syncthreads();

    for (int kc = 0; kc < 12; ++kc) {
        const int cur = kc & 1, nxt = cur ^ 1;
        const bool have = (kc + 1 < 12);

        // 1) issue global prefetch of chunk kc+1 into registers
        float4 f0, f1;
        bf16x8 wreg[6];
        if (have) {
            const float4* xp = (const float4*)(xg + (kc + 1) * 64);
            f0 = xp[0]; f1 = xp[1];
            #pragma unroll
            for (int j = 0; j < 6; ++j) {
                int c = tid + j * 256;
                int rw = c >> 3, cc = c & 7;
                wreg[j] = *(const bf16x8*)&Wt[(size_t)rw * CC + (kc + 1) * 64 + cc * 8];
            }
        }

        // 2) compute chunk kc from LDS (hides the prefetch latency)
        #pragma unroll
        for (int ks = 0; ks < 2; ++ks) {
            bf16x8 a = *(const bf16x8*)&xs[cur][(m0 + l15) * 72 + ks * 32 + quad * 8];
            #pragma unroll
            for (int nt = 0; nt < 6; ++nt) {
                bf16x8 bfr = *(const bf16x8*)
                    &ws[cur][(cg + nt * 16 + l15) * 72 + ks * 32 + quad * 8];
                acc[nt] = __builtin_amdgcn_mfma_f32_16x16x32_bf16(a, bfr, acc[nt], 0, 0, 0);
            }
        }

        // 3) write prefetched regs into the other buffer; one barrier
        if (have) {
            *(bf16x8*)&xs[nxt][ar * 72 + ac * 8] = cvt8(f0, f1);
            #pragma unroll
            for (int j = 0; j < 6; ++j) {
                int c = tid + j * 256;
                int rw = c >> 3, cc = c & 7;
                *(bf16x8*)&ws[nxt][rw * 72 + cc * 8] = wreg[j];
            }
        }
        __syncthreads();
    }

    // epilogue: C layout row = quad*4+r, col = l15 (+16*nt)
    #pragma unroll
    for (int nt = 0; nt < 6; ++nt) {
        int n = cg + nt * 16 + l15;
        #pragma unroll
        for (int r = 0; r < 4; ++r) {
            int row = row0 + m0 + quad * 4 + r;
            float vacc = acc[nt][r];
            if (n < 64)       qg[(size_t)row * HH + n] = f2bf(vacc * QSCALE);
            else if (n < 128) kg[(size_t)row * HH + (n - 64)] = f2bf(vacc);
            else              vts[(n - 128) * 40 + (m0 + quad * 4 + r)] = f2bf(vacc);
        }
    }
    __syncthreads();
    {   // cooperative write vt[b][h][t0..t0+31]
        int h = tid >> 2, p = tid & 3;
        int b = row0 >> 11, tl = row0 & 2047;
        bf16x8 v = *(const bf16x8*)&vts[h * 40 + p * 8];
        *(bf16x8*)&vtg[(size_t)b * (HH * TT) + (size_t)h * TT + tl + p * 8] = v;
    }
}

// ---------------------------------------------------------------------------
// attn_split: 32-query tile (2 waves) x 8-way s-split. 2048 blocks.
// K prefetched one step ahead; V issued before softmax. Zero __syncthreads.
// Softmax in base-2 (q carries log2e); single v_exp_f32 per element.
// ---------------------------------------------------------------------------
__global__ __launch_bounds__(128) void attn_split(const ushort* __restrict__ qg,
                                                  const ushort* __restrict__ kg,
                                                  const ushort* __restrict__ vtg,
                                                  float* __restrict__ Op,
                                                  float* __restrict__ ml) {
    const int qt2 = blockIdx.x, b = blockIdx.y, split = blockIdx.z;
    const int tid  = threadIdx.x;
    const int lane = tid & 63, w = tid >> 6;
    const int l15  = lane & 15, quad = lane >> 4;
    const int t0   = qt2 * 32;
    const int pidx = ((b * 64 + qt2) << 3) + split;

    const int ntile = (qt2 >> 1) + 1;     // 64-wide s-tiles covering s <= t0+31
    const int lo = (ntile * split) >> 3;
    const int hi = (ntile * (split + 1)) >> 3;

    if (lo >= hi) {   // empty split: zero partials
        float4 z = (float4){0.f, 0.f, 0.f, 0.f};
        float4* op4 = (float4*)(Op + (size_t)pidx * 2048);
        #pragma unroll
        for (int j = 0; j < 4; ++j) op4[tid * 4 + j] = z;
        if (tid < 32) {
            ml[pidx * 64 + tid]      = -1e30f;
            ml[pidx * 64 + 32 + tid] = 0.f;
        }
        return;
    }

    __shared__ ushort Ps[2][16 * 72];

    // Q fragments direct from global (q pre-scaled by 0.125*log2e)
    const ushort* qp = &qg[(size_t)(b * TT + t0 + w * 16 + l15) * HH + quad * 8];
    bf16x8 qa0 = *(const bf16x8*)qp;
    bf16x8 qa1 = *(const bf16x8*)(qp + 32);

    const ushort* kbb = &kg[(size_t)(b * TT + l15) * HH + quad * 8];
    const ushort* vbb = &vtg[(size_t)b * (HH * TT) + (size_t)l15 * TT + quad * 8];

    f32x4 po[4];
    #pragma unroll
    for (int i = 0; i < 4; ++i) po[i] = (f32x4){0.f, 0.f, 0.f, 0.f};
    float mrun[4] = {-1e30f, -1e30f, -1e30f, -1e30f};
    float lrun[4] = {0.f, 0.f, 0.f, 0.f};

    bf16x8 kb[8], vb[8];
    #pragma unroll
    for (int nt = 0; nt < 4; ++nt) {     // prime K for st = lo
        const ushort* kp = kbb + (size_t)(lo * 64 + nt * 16) * HH;
        kb[2 * nt]     = *(const bf16x8*)kp;
        kb[2 * nt + 1] = *(const bf16x8*)(kp + 32);
    }

    for (int st = lo; st < hi; ++st) {
        // S = Q K^T (uses prefetched kb)
        f32x4 sf[4];
        #pragma unroll
        for (int nt = 0; nt < 4; ++nt) {
            f32x4 z = (f32x4){0.f, 0.f, 0.f, 0.f};
            z = __builtin_amdgcn_mfma_f32_16x16x32_bf16(qa0, kb[2 * nt], z, 0, 0, 0);
            sf[nt] = __builtin_amdgcn_mfma_f32_16x16x32_bf16(qa1, kb[2 * nt + 1], z, 0, 0, 0);
        }
        // prefetch next K (latency hidden under softmax + PV)
        if (st + 1 < hi) {
            #pragma unroll
            for (int nt = 0; nt < 4; ++nt) {
                const ushort* kp = kbb + (size_t)((st + 1) * 64 + nt * 16) * HH;
                kb[2 * nt]     = *(const bf16x8*)kp;
                kb[2 * nt + 1] = *(const bf16x8*)(kp + 32);
            }
        }
        // issue V loads for this step (consumed after softmax + P transpose)
        #pragma unroll
        for (int jj = 0; jj < 4; ++jj) {
            const ushort* vp = vbb + (size_t)(jj * 16) * TT + st * 64;
            vb[2 * jj]     = *(const bf16x8*)vp;
            vb[2 * jj + 1] = *(const bf16x8*)(vp + 32);
        }

        // causal mask (diagonal tile lives in the last split) + online softmax
        float p[4][4];
        float rm[4] = {-1e30f, -1e30f, -1e30f, -1e30f};
        if (st == ntile - 1) {
            #pragma unroll
            for (int nt = 0; nt < 4; ++nt) {
                int s_abs = st * 64 + nt * 16 + l15;
                #pragma unroll
                for (int r = 0; r < 4; ++r) {
                    int t_abs = t0 + w * 16 + quad * 4 + r;
                    float v = (s_abs > t_abs) ? -1e30f : sf[nt][r];
                    p[nt][r] = v;
                    rm[r] = fmaxf(rm[r], v);
                }
            }
        } else {
            #pragma unroll
            for (int nt = 0; nt < 4; ++nt)
                #pragma unroll
                for (int r = 0; r < 4; ++r) {
                    p[nt][r] = sf[nt][r];
                    rm[r] = fmaxf(rm[r], sf[nt][r]);
                }
        }
        float alpha[4], rs[4] = {0.f, 0.f, 0.f, 0.f};
        #pragma unroll
        for (int r = 0; r < 4; ++r) {
            float v = rm[r];
            v = fmaxf(v, __shfl_xor(v, 1, 64));
            v = fmaxf(v, __shfl_xor(v, 2, 64));
            v = fmaxf(v, __shfl_xor(v, 4, 64));
            v = fmaxf(v, __shfl_xor(v, 8, 64));
            float mnew = fmaxf(mrun[r], v);
            alpha[r] = fexp2(mrun[r] - mnew);
            mrun[r] = mnew;
        }
        #pragma unroll
        for (int nt = 0; nt < 4; ++nt)
            #pragma unroll
            for (int r = 0; r < 4; ++r) {
                float e = fexp2(p[nt][r] - mrun[r]);
                p[nt][r] = e;
                rs[r] += e;
            }
        #pragma unroll
        for (int r = 0; r < 4; ++r) {
            float v = rs[r];
            v += __shfl_xor(v, 1, 64);
            v += __shfl_xor(v, 2, 64);
            v += __shfl_xor(v, 4, 64);
            v += __shfl_xor(v, 8, 64);
            lrun[r] = lrun[r] * alpha[r] + v;
        }
        #pragma unroll
        for (int jj = 0; jj < 4; ++jj)
            #pragma unroll
            for (int r = 0; r < 4; ++r)
                po[jj][r] *= alpha[r];

        // P: C-layout regs -> per-wave LDS -> A-layout frags (no barrier)
        #pragma unroll
        for (int nt = 0; nt < 4; ++nt)
            #pragma unroll
            for (int r = 0; r < 4; ++r)
                Ps[w][(quad * 4 + r) * 72 + nt * 16 + l15] = f2bf(p[nt][r]);
        bf16x8 pa0 = *(const bf16x8*)&Ps[w][l15 * 72 + quad * 8];
        bf16x8 pa1 = *(const bf16x8*)&Ps[w][l15 * 72 + 32 + quad * 8];

        // O += P V (uses vb issued before softmax)
        #pragma unroll
        for (int jj = 0; jj < 4; ++jj) {
            po[jj] = __builtin_amdgcn_mfma_f32_16x16x32_bf16(pa0, vb[2 * jj], po[jj], 0, 0, 0);
            po[jj] = __builtin_amdgcn_mfma_f32_16x16x32_bf16(pa1, vb[2 * jj + 1], po[jj], 0, 0, 0);
        }
    }

    // write partials: unnormalized O + per-row m, l
    #pragma unroll
    for (int jj = 0; jj < 4; ++jj)
        #pragma unroll
        for (int r = 0; r < 4; ++r)
            Op[(size_t)pidx * 2048 + (w * 16 + quad * 4 + r) * 64 + jj * 16 + l15] =
                po[jj][r];
    if (l15 == 0) {
        #pragma unroll
        for (int r = 0; r < 4; ++r) {
            int row = w * 16 + quad * 4 + r;
            ml[pidx * 64 + row]      = mrun[r];
            ml[pidx * 64 + 32 + row] = lrun[r];
        }
    }
}

// ---------------------------------------------------------------------------
// attn_merge: combine NSPLIT partials per row; one wave per output row.
// ---------------------------------------------------------------------------
__global__ __launch_bounds__(256) void attn_merge(const float* __restrict__ Op,
                                                  const float* __restrict__ ml,
                                                  float* __restrict__ out) {
    const int tid = threadIdx.x;
    const int w = tid >> 6, lane = tid & 63;
    const int row = blockIdx.x * 4 + w;        // 0..8191
    const int b = row >> 11, t = row & 2047;
    const int qt2 = t >> 5, rl = t & 31;
    const int pbase = ((b * 64 + qt2) << 3);

    float m[NSPLIT], l[NSPLIT];
    #pragma unroll
    for (int i = 0; i < NSPLIT; ++i) {
        m[i] = ml[(pbase + i) * 64 + rl];
        l[i] = ml[(pbase + i) * 64 + 32 + rl];
    }
    float M = -1e30f;
    #pragma unroll
    for (int i = 0; i < NSPLIT; ++i) M = fmaxf(M, m[i]);
    float wgt[NSPLIT], L = 0.f;
    #pragma unroll
    for (int i = 0; i < NSPLIT; ++i) {
        wgt[i] = fexp2(m[i] - M);     // base-2 domain (matches attn_split)
        L += wgt[i] * l[i];
    }
    float acc = 0.f;
    #pragma unroll
    for (int i = 0; i < NSPLIT; ++i)
        acc += wgt[i] * Op[(size_t)(pbase + i) * 2048 + rl * 64 + lane];
    out[(size_t)row * HH + lane] = acc / L;
}

// ---------------------------------------------------------------------------
extern "C" void kernel_launch(void* const* d_in, const int* in_sizes, int n_in,
                              void* d_out, int out_size, void* d_ws, size_t ws_size,
                              hipStream_t stream)
{
    const float* x  = (const float*)d_in[0];
    const float* Wq = (const float*)d_in[1];
    const float* Wk = (const float*)d_in[2];
    const float* Wv = (const float*)d_in[3];
    float* out = (float*)d_out;

    // ws layout: qg 1MB | kg 1MB | vtg 1MB | Wt 288KB | Op 16.8MB | ml 512KB
    ushort* qg  = (ushort*)d_ws;
    ushort* kg  = qg  + (size_t)BB * TT * HH;
    ushort* vtg = kg  + (size_t)BB * TT * HH;
    ushort* Wt  = vtg + (size_t)BB * TT * HH;
    float*  Op  = (float*)(Wt + (size_t)3 * HH * CC);
    float*  ml  = Op + (size_t)2048 * 2048;

    prep_w    <<<dim3(12, 3),           dim3(256), 0, stream>>>(Wq, Wk, Wv, Wt);
    qkv_mfma  <<<dim3((BB * TT) / 32),  dim3(256), 0, stream>>>(x, Wt, qg, kg, vtg);
    attn_split<<<dim3(64, BB, NSPLIT),  dim3(128), 0, stream>>>(qg, kg, vtg, Op, ml);
    attn_merge<<<dim3((BB * TT) / 4),   dim3(256), 0, stream>>>(Op, ml, out);
}

// Round 10
// 115.555 us; speedup vs baseline: 2.3262x; 1.0283x over previous
//
#include <hip/hip_runtime.h>
#include <hip/hip_bf16.h>
#include <math.h>

constexpr int BB = 4;     // batch
constexpr int TT = 2048;  // sequence
constexpr int CC = 768;   // channels
constexpr int HH = 64;    // head dim
constexpr int NSPLIT = 4; // attention s-splits (in-block, 8 waves = 4 x wave-pair)

// Softmax is computed in base-2: q carries 0.125*log2(e), exp -> exp2.
#define QSCALE 0.1803368801111204f   // 0.125 * log2(e)

typedef __attribute__((ext_vector_type(8))) short bf16x8;   // 8 bf16 = 4 VGPR
typedef __attribute__((ext_vector_type(4))) float f32x4;    // MFMA C/D

__device__ inline ushort f2bf(float f) {   // fp32 -> bf16 RNE (scalar)
    uint u = __float_as_uint(f);
    u += 0x7fffu + ((u >> 16) & 1u);
    return (ushort)(u >> 16);
}

__device__ inline float fexp2(float x) { return __builtin_amdgcn_exp2f(x); }

__device__ inline bf16x8 cvt8(const float4 a, const float4 b) {  // packed cvt
    union { bf16x8 v; __hip_bfloat162 h[4]; } u;
    u.h[0] = __float22bfloat162_rn(make_float2(a.x, a.y));
    u.h[1] = __float22bfloat162_rn(make_float2(a.z, a.w));
    u.h[2] = __float22bfloat162_rn(make_float2(b.x, b.y));
    u.h[3] = __float22bfloat162_rn(make_float2(b.z, b.w));
    return u.v;
}

// ---------------------------------------------------------------------------
// prep_w: W[768][64] fp32 -> Wt[mat][n][768] bf16 (transposed, k-contiguous)
// ---------------------------------------------------------------------------
__global__ __launch_bounds__(256) void prep_w(const float* __restrict__ Wq,
                                              const float* __restrict__ Wk,
                                              const float* __restrict__ Wv,
                                              ushort* __restrict__ Wt) {
    const int k0  = blockIdx.x * 64;
    const int mat = blockIdx.y;
    const float* W = (mat == 0) ? Wq : (mat == 1) ? Wk : Wv;
    __shared__ ushort tile[64 * 66];
    const int tid = threadIdx.x;

    for (int i = tid; i < 1024; i += 256) {
        int kk = i >> 4, c = i & 15;
        float4 f = ((const float4*)W)[(k0 + kk) * 16 + c];
        ushort* d = &tile[kk * 66 + c * 4];
        d[0] = f2bf(f.x); d[1] = f2bf(f.y); d[2] = f2bf(f.z); d[3] = f2bf(f.w);
    }
    __syncthreads();
    for (int i = tid; i < 512; i += 256) {
        int n = i >> 3, c8 = i & 7;
        bf16x8 v;
        #pragma unroll
        for (int j = 0; j < 8; ++j)
            ((ushort*)&v)[j] = tile[(c8 * 8 + j) * 66 + n];
        *(bf16x8*)&Wt[(size_t)(mat * 64 + n) * CC + k0 + c8 * 8] = v;
    }
}

// ---------------------------------------------------------------------------
// qkv_mfma (m97-style, unchanged from R9): 32 rows x 192 cols per block,
// BK=64 double-buffered LDS, register prefetch, one barrier per chunk.
// ---------------------------------------------------------------------------
__global__ __launch_bounds__(256) void qkv_mfma(const float* __restrict__ x,
                                                const ushort* __restrict__ Wt,
                                                ushort* __restrict__ qg,
                                                ushort* __restrict__ kg,
                                                ushort* __restrict__ vtg) {
    __shared__ ushort xs[2][32 * 72];
    __shared__ ushort ws[2][192 * 72];
    __shared__ ushort vts[64 * 40];      // [h][t-local 0..31]
    const int tid  = threadIdx.x;
    const int row0 = blockIdx.x * 32;
    const int lane = tid & 63, w = tid >> 6;
    const int l15  = lane & 15, quad = lane >> 4;
    const int m0   = (w & 1) * 16;       // row sub-tile
    const int cg   = (w >> 1) * 96;      // col half

    f32x4 acc[6];
    #pragma unroll
    for (int i = 0; i < 6; ++i) acc[i] = (f32x4){0.f, 0.f, 0.f, 0.f};

    const int ar = tid >> 3, ac = tid & 7;
    const float* xg = x + (size_t)(row0 + ar) * CC + ac * 8;

    {
        const float4* xp = (const float4*)xg;
        *(bf16x8*)&xs[0][ar * 72 + ac * 8] = cvt8(xp[0], xp[1]);
        #pragma unroll
        for (int j = 0; j < 6; ++j) {
            int c = tid + j * 256;
            int rw = c >> 3, cc = c & 7;
            *(bf16x8*)&ws[0][rw * 72 + cc * 8] =
                *(const bf16x8*)&Wt[(size_t)rw * CC + cc * 8];
        }
    }
    __syncthreads();

    for (int kc = 0; kc < 12; ++kc) {
        const int cur = kc & 1, nxt = cur ^ 1;
        const bool have = (kc + 1 < 12);

        float4 f0, f1;
        bf16x8 wreg[6];
        if (have) {
            const float4* xp = (const float4*)(xg + (kc + 1) * 64);
            f0 = xp[0]; f1 = xp[1];
            #pragma unroll
            for (int j = 0; j < 6; ++j) {
                int c = tid + j * 256;
                int rw = c >> 3, cc = c & 7;
                wreg[j] = *(const bf16x8*)&Wt[(size_t)rw * CC + (kc + 1) * 64 + cc * 8];
            }
        }

        #pragma unroll
        for (int ks = 0; ks < 2; ++ks) {
            bf16x8 a = *(const bf16x8*)&xs[cur][(m0 + l15) * 72 + ks * 32 + quad * 8];
            #pragma unroll
            for (int nt = 0; nt < 6; ++nt) {
                bf16x8 bfr = *(const bf16x8*)
                    &ws[cur][(cg + nt * 16 + l15) * 72 + ks * 32 + quad * 8];
                acc[nt] = __builtin_amdgcn_mfma_f32_16x16x32_bf16(a, bfr, acc[nt], 0, 0, 0);
            }
        }

        if (have) {
            *(bf16x8*)&xs[nxt][ar * 72 + ac * 8] = cvt8(f0, f1);
            #pragma unroll
            for (int j = 0; j < 6; ++j) {
                int c = tid + j * 256;
                int rw = c >> 3, cc = c & 7;
                *(bf16x8*)&ws[nxt][rw * 72 + cc * 8] = wreg[j];
            }
        }
        __syncthreads();
    }

    #pragma unroll
    for (int nt = 0; nt < 6; ++nt) {
        int n = cg + nt * 16 + l15;
        #pragma unroll
        for (int r = 0; r < 4; ++r) {
            int row = row0 + m0 + quad * 4 + r;
            float vacc = acc[nt][r];
            if (n < 64)       qg[(size_t)row * HH + n] = f2bf(vacc * QSCALE);
            else if (n < 128) kg[(size_t)row * HH + (n - 64)] = f2bf(vacc);
            else              vts[(n - 128) * 40 + (m0 + quad * 4 + r)] = f2bf(vacc);
        }
    }
    __syncthreads();
    {
        int h = tid >> 2, p = tid & 3;
        int b = row0 >> 11, tl = row0 & 2047;
        bf16x8 v = *(const bf16x8*)&vts[h * 40 + p * 8];
        *(bf16x8*)&vtg[(size_t)b * (HH * TT) + (size_t)h * TT + tl + p * 8] = v;
    }
}

// ---------------------------------------------------------------------------
// attn_block: one block per (qt2, b) group, 512 threads = 8 waves.
// Waves (2w, 2w+1) form wave-pair handling s-split w (w = 0..3) exactly like
// R9's attn_split (K prefetch, V early-issue, base-2 softmax, per-wave Ps).
// Partials go to LDS; one __syncthreads; in-block merge writes out.
// No global Op/ml, no merge kernel, no cross-block communication.
// ---------------------------------------------------------------------------
__global__ __launch_bounds__(512) void attn_block(const ushort* __restrict__ qg,
                                                  const ushort* __restrict__ kg,
                                                  const ushort* __restrict__ vtg,
                                                  float* __restrict__ out) {
    const int qt2 = blockIdx.x, b = blockIdx.y;
    const int tid  = threadIdx.x;
    const int lane = tid & 63, w = tid >> 6;      // w = 0..7
    const int split = w >> 1, ws2 = w & 1;        // split 0..3, 16-row half
    const int l15  = lane & 15, quad = lane >> 4;
    const int t0   = qt2 * 32;

    const int ntile = (qt2 >> 1) + 1;             // 64-wide s-tiles
    const int lo = (ntile * split) >> 2;
    const int hi = (ntile * (split + 1)) >> 2;

    __shared__ ushort Ps[8][16 * 72];             // per-wave P transpose
    __shared__ float  Opart[NSPLIT][32 * 64];     // per-split partial O
    __shared__ float  mlm[NSPLIT][32];            // per-split row max
    __shared__ float  mll[NSPLIT][32];            // per-split row sum

    if (lo >= hi) {
        // empty split: flag l=0 (merge skips Opart read)
        if (ws2 == 0 && lane < 32) {
            mlm[split][lane] = -1e30f;
            mll[split][lane] = 0.f;
        }
    } else {
        // Q fragments direct from global (q pre-scaled by 0.125*log2e)
        const ushort* qp = &qg[(size_t)(b * TT + t0 + ws2 * 16 + l15) * HH + quad * 8];
        bf16x8 qa0 = *(const bf16x8*)qp;
        bf16x8 qa1 = *(const bf16x8*)(qp + 32);

        const ushort* kbb = &kg[(size_t)(b * TT + l15) * HH + quad * 8];
        const ushort* vbb = &vtg[(size_t)b * (HH * TT) + (size_t)l15 * TT + quad * 8];

        f32x4 po[4];
        #pragma unroll
        for (int i = 0; i < 4; ++i) po[i] = (f32x4){0.f, 0.f, 0.f, 0.f};
        float mrun[4] = {-1e30f, -1e30f, -1e30f, -1e30f};
        float lrun[4] = {0.f, 0.f, 0.f, 0.f};

        bf16x8 kb[8], vb[8];
        #pragma unroll
        for (int nt = 0; nt < 4; ++nt) {     // prime K for st = lo
            const ushort* kp = kbb + (size_t)(lo * 64 + nt * 16) * HH;
            kb[2 * nt]     = *(const bf16x8*)kp;
            kb[2 * nt + 1] = *(const bf16x8*)(kp + 32);
        }

        for (int st = lo; st < hi; ++st) {
            // S = Q K^T (uses prefetched kb)
            f32x4 sf[4];
            #pragma unroll
            for (int nt = 0; nt < 4; ++nt) {
                f32x4 z = (f32x4){0.f, 0.f, 0.f, 0.f};
                z = __builtin_amdgcn_mfma_f32_16x16x32_bf16(qa0, kb[2 * nt], z, 0, 0, 0);
                sf[nt] = __builtin_amdgcn_mfma_f32_16x16x32_bf16(qa1, kb[2 * nt + 1], z, 0, 0, 0);
            }
            // prefetch next K (latency hidden under softmax + PV)
            if (st + 1 < hi) {
                #pragma unroll
                for (int nt = 0; nt < 4; ++nt) {
                    const ushort* kp = kbb + (size_t)((st + 1) * 64 + nt * 16) * HH;
                    kb[2 * nt]     = *(const bf16x8*)kp;
                    kb[2 * nt + 1] = *(const bf16x8*)(kp + 32);
                }
            }
            // issue V loads for this step (consumed after softmax + P transpose)
            #pragma unroll
            for (int jj = 0; jj < 4; ++jj) {
                const ushort* vp = vbb + (size_t)(jj * 16) * TT + st * 64;
                vb[2 * jj]     = *(const bf16x8*)vp;
                vb[2 * jj + 1] = *(const bf16x8*)(vp + 32);
            }

            // causal mask (diagonal tile in last split) + online softmax
            float p[4][4];
            float rm[4] = {-1e30f, -1e30f, -1e30f, -1e30f};
            if (st == ntile - 1) {
                #pragma unroll
                for (int nt = 0; nt < 4; ++nt) {
                    int s_abs = st * 64 + nt * 16 + l15;
                    #pragma unroll
                    for (int r = 0; r < 4; ++r) {
                        int t_abs = t0 + ws2 * 16 + quad * 4 + r;
                        float v = (s_abs > t_abs) ? -1e30f : sf[nt][r];
                        p[nt][r] = v;
                        rm[r] = fmaxf(rm[r], v);
                    }
                }
            } else {
                #pragma unroll
                for (int nt = 0; nt < 4; ++nt)
                    #pragma unroll
                    for (int r = 0; r < 4; ++r) {
                        p[nt][r] = sf[nt][r];
                        rm[r] = fmaxf(rm[r], sf[nt][r]);
                    }
            }
            float alpha[4], rs[4] = {0.f, 0.f, 0.f, 0.f};
            #pragma unroll
            for (int r = 0; r < 4; ++r) {
                float v = rm[r];
                v = fmaxf(v, __shfl_xor(v, 1, 64));
                v = fmaxf(v, __shfl_xor(v, 2, 64));
                v = fmaxf(v, __shfl_xor(v, 4, 64));
                v = fmaxf(v, __shfl_xor(v, 8, 64));
                float mnew = fmaxf(mrun[r], v);
                alpha[r] = fexp2(mrun[r] - mnew);
                mrun[r] = mnew;
            }
            #pragma unroll
            for (int nt = 0; nt < 4; ++nt)
                #pragma unroll
                for (int r = 0; r < 4; ++r) {
                    float e = fexp2(p[nt][r] - mrun[r]);
                    p[nt][r] = e;
                    rs[r] += e;
                }
            #pragma unroll
            for (int r = 0; r < 4; ++r) {
                float v = rs[r];
                v += __shfl_xor(v, 1, 64);
                v += __shfl_xor(v, 2, 64);
                v += __shfl_xor(v, 4, 64);
                v += __shfl_xor(v, 8, 64);
                lrun[r] = lrun[r] * alpha[r] + v;
            }
            #pragma unroll
            for (int jj = 0; jj < 4; ++jj)
                #pragma unroll
                for (int r = 0; r < 4; ++r)
                    po[jj][r] *= alpha[r];

            // P: C-layout regs -> per-wave LDS -> A-layout frags (no barrier)
            #pragma unroll
            for (int nt = 0; nt < 4; ++nt)
                #pragma unroll
                for (int r = 0; r < 4; ++r)
                    Ps[w][(quad * 4 + r) * 72 + nt * 16 + l15] = f2bf(p[nt][r]);
            bf16x8 pa0 = *(const bf16x8*)&Ps[w][l15 * 72 + quad * 8];
            bf16x8 pa1 = *(const bf16x8*)&Ps[w][l15 * 72 + 32 + quad * 8];

            // O += P V (uses vb issued before softmax)
            #pragma unroll
            for (int jj = 0; jj < 4; ++jj) {
                po[jj] = __builtin_amdgcn_mfma_f32_16x16x32_bf16(pa0, vb[2 * jj], po[jj], 0, 0, 0);
                po[jj] = __builtin_amdgcn_mfma_f32_16x16x32_bf16(pa1, vb[2 * jj + 1], po[jj], 0, 0, 0);
            }
        }

        // write partials to LDS: unnormalized O + per-row m, l
        #pragma unroll
        for (int jj = 0; jj < 4; ++jj)
            #pragma unroll
            for (int r = 0; r < 4; ++r)
                Opart[split][(ws2 * 16 + quad * 4 + r) * 64 + jj * 16 + l15] = po[jj][r];
        if (l15 == 0) {
            #pragma unroll
            for (int r = 0; r < 4; ++r) {
                int row = ws2 * 16 + quad * 4 + r;
                mlm[split][row] = mrun[r];
                mll[split][row] = lrun[r];
            }
        }
    }

    __syncthreads();

    // ---- in-block merge: 2048 output elems by 512 threads ----
    #pragma unroll
    for (int j = 0; j < 4; ++j) {
        int e  = tid + j * 512;
        int rr = e >> 6, h = e & 63;
        float M = -1e30f;
        #pragma unroll
        for (int i = 0; i < NSPLIT; ++i) M = fmaxf(M, mlm[i][rr]);
        float L = 0.f, acc = 0.f;
        #pragma unroll
        for (int i = 0; i < NSPLIT; ++i) {
            float li = mll[i][rr];
            if (li > 0.f) {
                float wgt = fexp2(mlm[i][rr] - M);
                L   += wgt * li;
                acc += wgt * Opart[i][rr * 64 + h];
            }
        }
        out[(size_t)(b * TT + t0 + rr) * HH + h] = acc / L;
    }
}

// ---------------------------------------------------------------------------
extern "C" void kernel_launch(void* const* d_in, const int* in_sizes, int n_in,
                              void* d_out, int out_size, void* d_ws, size_t ws_size,
                              hipStream_t stream)
{
    const float* x  = (const float*)d_in[0];
    const float* Wq = (const float*)d_in[1];
    const float* Wk = (const float*)d_in[2];
    const float* Wv = (const float*)d_in[3];
    float* out = (float*)d_out;

    // ws layout: qg 1MB | kg 1MB | vtg 1MB | Wt 288KB
    ushort* qg  = (ushort*)d_ws;
    ushort* kg  = qg  + (size_t)BB * TT * HH;
    ushort* vtg = kg  + (size_t)BB * TT * HH;
    ushort* Wt  = vtg + (size_t)BB * TT * HH;

    prep_w    <<<dim3(12, 3),          dim3(256), 0, stream>>>(Wq, Wk, Wv, Wt);
    qkv_mfma  <<<dim3((BB * TT) / 32), dim3(256), 0, stream>>>(x, Wt, qg, kg, vtg);
    attn_block<<<dim3(64, BB),         dim3(512), 0, stream>>>(qg, kg, vtg, out);
}

// Round 11
// 114.672 us; speedup vs baseline: 2.3441x; 1.0077x over previous
//
#include <hip/hip_runtime.h>
#include <hip/hip_bf16.h>
#include <math.h>

constexpr int BB = 4;     // batch
constexpr int TT = 2048;  // sequence
constexpr int CC = 768;   // channels
constexpr int HH = 64;    // head dim
constexpr int NSPLIT = 4; // attention s-splits (one wave each, in-block merge)

// Softmax is computed in base-2: q carries 0.125*log2(e), exp -> exp2.
#define QSCALE 0.1803368801111204f   // 0.125 * log2(e)

typedef __attribute__((ext_vector_type(8))) short bf16x8;   // 8 bf16 = 4 VGPR
typedef __attribute__((ext_vector_type(4))) float f32x4;    // MFMA C/D

__device__ inline ushort f2bf(float f) {   // fp32 -> bf16 RNE (scalar)
    uint u = __float_as_uint(f);
    u += 0x7fffu + ((u >> 16) & 1u);
    return (ushort)(u >> 16);
}

__device__ inline float fexp2(float x) { return __builtin_amdgcn_exp2f(x); }

__device__ inline bf16x8 cvt8(const float4 a, const float4 b) {  // packed cvt
    union { bf16x8 v; __hip_bfloat162 h[4]; } u;
    u.h[0] = __float22bfloat162_rn(make_float2(a.x, a.y));
    u.h[1] = __float22bfloat162_rn(make_float2(a.z, a.w));
    u.h[2] = __float22bfloat162_rn(make_float2(b.x, b.y));
    u.h[3] = __float22bfloat162_rn(make_float2(b.z, b.w));
    return u.v;
}

// ---------------------------------------------------------------------------
// prep_w: W[768][64] fp32 -> Wt[mat][n][768] bf16 (transposed, k-contiguous)
// ---------------------------------------------------------------------------
__global__ __launch_bounds__(256) void prep_w(const float* __restrict__ Wq,
                                              const float* __restrict__ Wk,
                                              const float* __restrict__ Wv,
                                              ushort* __restrict__ Wt) {
    const int k0  = blockIdx.x * 64;
    const int mat = blockIdx.y;
    const float* W = (mat == 0) ? Wq : (mat == 1) ? Wk : Wv;
    __shared__ ushort tile[64 * 66];
    const int tid = threadIdx.x;

    for (int i = tid; i < 1024; i += 256) {
        int kk = i >> 4, c = i & 15;
        float4 f = ((const float4*)W)[(k0 + kk) * 16 + c];
        ushort* d = &tile[kk * 66 + c * 4];
        d[0] = f2bf(f.x); d[1] = f2bf(f.y); d[2] = f2bf(f.z); d[3] = f2bf(f.w);
    }
    __syncthreads();
    for (int i = tid; i < 512; i += 256) {
        int n = i >> 3, c8 = i & 7;
        bf16x8 v;
        #pragma unroll
        for (int j = 0; j < 8; ++j)
            ((ushort*)&v)[j] = tile[(c8 * 8 + j) * 66 + n];
        *(bf16x8*)&Wt[(size_t)(mat * 64 + n) * CC + k0 + c8 * 8] = v;
    }
}

// ---------------------------------------------------------------------------
// qkv_mfma v6: 512 blocks = (row-group of 32) x (col-group of 96).
// LDS 42 KB -> 2 blocks/CU co-resident (8 waves/CU): barrier drains overlap
// across blocks. BK=64 double-buffered, register prefetch, 1 barrier/chunk.
// Wave = 16 rows x 48 cols: 6 MFMAs per chunk vs 8 ds_read_b128.
// ---------------------------------------------------------------------------
__global__ __launch_bounds__(256) void qkv_mfma(const float* __restrict__ x,
                                                const ushort* __restrict__ Wt,
                                                ushort* __restrict__ qg,
                                                ushort* __restrict__ kg,
                                                ushort* __restrict__ vtg) {
    __shared__ ushort xs[2][32 * 72];    //  9.2 KB
    __shared__ ushort ws[2][96 * 72];    // 27.6 KB
    __shared__ ushort vts[64 * 40];      //  5.1 KB [h][t-local 0..31]
    const int tid  = threadIdx.x;
    const int bx   = blockIdx.x;
    const int row0 = (bx >> 1) * 32;
    const int cg2  = bx & 1;             // col group: cols cg2*96 .. +96
    const int lane = tid & 63, w = tid >> 6;
    const int l15  = lane & 15, quad = lane >> 4;
    const int m0   = (w & 1) * 16;       // row sub-tile
    const int cgw  = (w >> 1) * 48;      // col sub-group within the 96

    f32x4 acc[3];
    #pragma unroll
    for (int i = 0; i < 3; ++i) acc[i] = (f32x4){0.f, 0.f, 0.f, 0.f};

    const int ar = tid >> 3, ac = tid & 7;
    const float*  xg  = x + (size_t)(row0 + ar) * CC + ac * 8;
    const ushort* wtg = Wt + (size_t)(cg2 * 96) * CC;

    {   // prologue: stage chunk 0
        const float4* xp = (const float4*)xg;
        *(bf16x8*)&xs[0][ar * 72 + ac * 8] = cvt8(xp[0], xp[1]);
        #pragma unroll
        for (int j = 0; j < 3; ++j) {
            int c = tid + j * 256;                   // 768 16B-chunks
            int rw = c >> 3, cc = c & 7;
            *(bf16x8*)&ws[0][rw * 72 + cc * 8] =
                *(const bf16x8*)&wtg[(size_t)rw * CC + cc * 8];
        }
    }
    __syncthreads();

    for (int kc = 0; kc < 12; ++kc) {
        const int cur = kc & 1, nxt = cur ^ 1;
        const bool have = (kc + 1 < 12);

        float4 f0, f1;
        bf16x8 wreg[3];
        if (have) {
            const float4* xp = (const float4*)(xg + (kc + 1) * 64);
            f0 = xp[0]; f1 = xp[1];
            #pragma unroll
            for (int j = 0; j < 3; ++j) {
                int c = tid + j * 256;
                int rw = c >> 3, cc = c & 7;
                wreg[j] = *(const bf16x8*)&wtg[(size_t)rw * CC + (kc + 1) * 64 + cc * 8];
            }
        }

        #pragma unroll
        for (int ks = 0; ks < 2; ++ks) {
            bf16x8 a = *(const bf16x8*)&xs[cur][(m0 + l15) * 72 + ks * 32 + quad * 8];
            #pragma unroll
            for (int nt = 0; nt < 3; ++nt) {
                bf16x8 bfr = *(const bf16x8*)
                    &ws[cur][(cgw + nt * 16 + l15) * 72 + ks * 32 + quad * 8];
                acc[nt] = __builtin_amdgcn_mfma_f32_16x16x32_bf16(a, bfr, acc[nt], 0, 0, 0);
            }
        }

        if (have) {
            *(bf16x8*)&xs[nxt][ar * 72 + ac * 8] = cvt8(f0, f1);
            #pragma unroll
            for (int j = 0; j < 3; ++j) {
                int c = tid + j * 256;
                int rw = c >> 3, cc = c & 7;
                *(bf16x8*)&ws[nxt][rw * 72 + cc * 8] = wreg[j];
            }
        }
        __syncthreads();
    }

    // epilogue: C layout row = quad*4+r, global col = cg2*96 + cgw + nt*16 + l15
    #pragma unroll
    for (int nt = 0; nt < 3; ++nt) {
        int n = cg2 * 96 + cgw + nt * 16 + l15;
        #pragma unroll
        for (int r = 0; r < 4; ++r) {
            int row = row0 + m0 + quad * 4 + r;
            float vacc = acc[nt][r];
            if (n < 64)       qg[(size_t)row * HH + n] = f2bf(vacc * QSCALE);
            else if (n < 128) kg[(size_t)row * HH + (n - 64)] = f2bf(vacc);
            else              vts[(n - 128) * 40 + (m0 + quad * 4 + r)] = f2bf(vacc);
        }
    }
    if (cg2 == 1) {   // only col-group 1 produced v; block-uniform branch
        __syncthreads();
        int h = tid >> 2, p = tid & 3;
        int b = row0 >> 11, tl = row0 & 2047;
        bf16x8 v = *(const bf16x8*)&vts[h * 40 + p * 8];
        *(bf16x8*)&vtg[(size_t)b * (HH * TT) + (size_t)h * TT + tl + p * 8] = v;
    }
}

// ---------------------------------------------------------------------------
// attn_block v2: one block per (16-row q-tile, b) = 512 blocks, 256 threads.
// Wave w = s-split w (0..3) over the causal s-range; same inner loop as R9
// (K prefetch, V early-issue, base-2 softmax, per-wave Ps transpose).
// Partials in LDS (26 KB -> multiple blocks/CU, qt-mixed for balance);
// one __syncthreads; in-block merge writes out.
// ---------------------------------------------------------------------------
__global__ __launch_bounds__(256) void attn_block(const ushort* __restrict__ qg,
                                                  const ushort* __restrict__ kg,
                                                  const ushort* __restrict__ vtg,
                                                  float* __restrict__ out) {
    const int qt = blockIdx.x, b = blockIdx.y;   // qt: 16-row tile, 0..127
    const int tid  = threadIdx.x;
    const int lane = tid & 63, w = tid >> 6;     // w = split 0..3
    const int l15  = lane & 15, quad = lane >> 4;
    const int t0   = qt * 16;

    const int ntile = (qt >> 2) + 1;             // 64-wide s-tiles
    const int lo = (ntile * w) >> 2;
    const int hi = (ntile * (w + 1)) >> 2;

    __shared__ ushort Ps[NSPLIT][16 * 72];       // per-wave P transpose
    __shared__ float  Opart[NSPLIT][16 * 64];    // per-split partial O
    __shared__ float  mlm[NSPLIT][16];           // per-split row max
    __shared__ float  mll[NSPLIT][16];           // per-split row sum

    if (lo >= hi) {
        if (lane < 16) {
            mlm[w][lane] = -1e30f;
            mll[w][lane] = 0.f;                  // merge skips Opart read
        }
    } else {
        // Q fragments direct from global (q pre-scaled by 0.125*log2e)
        const ushort* qp = &qg[(size_t)(b * TT + t0 + l15) * HH + quad * 8];
        bf16x8 qa0 = *(const bf16x8*)qp;
        bf16x8 qa1 = *(const bf16x8*)(qp + 32);

        const ushort* kbb = &kg[(size_t)(b * TT + l15) * HH + quad * 8];
        const ushort* vbb = &vtg[(size_t)b * (HH * TT) + (size_t)l15 * TT + quad * 8];

        f32x4 po[4];
        #pragma unroll
        for (int i = 0; i < 4; ++i) po[i] = (f32x4){0.f, 0.f, 0.f, 0.f};
        float mrun[4] = {-1e30f, -1e30f, -1e30f, -1e30f};
        float lrun[4] = {0.f, 0.f, 0.f, 0.f};

        bf16x8 kb[8], vb[8];
        #pragma unroll
        for (int nt = 0; nt < 4; ++nt) {     // prime K for st = lo
            const ushort* kp = kbb + (size_t)(lo * 64 + nt * 16) * HH;
            kb[2 * nt]     = *(const bf16x8*)kp;
            kb[2 * nt + 1] = *(const bf16x8*)(kp + 32);
        }

        for (int st = lo; st < hi; ++st) {
            // S = Q K^T (uses prefetched kb)
            f32x4 sf[4];
            #pragma unroll
            for (int nt = 0; nt < 4; ++nt) {
                f32x4 z = (f32x4){0.f, 0.f, 0.f, 0.f};
                z = __builtin_amdgcn_mfma_f32_16x16x32_bf16(qa0, kb[2 * nt], z, 0, 0, 0);
                sf[nt] = __builtin_amdgcn_mfma_f32_16x16x32_bf16(qa1, kb[2 * nt + 1], z, 0, 0, 0);
            }
            // prefetch next K (latency hidden under softmax + PV)
            if (st + 1 < hi) {
                #pragma unroll
                for (int nt = 0; nt < 4; ++nt) {
                    const ushort* kp = kbb + (size_t)((st + 1) * 64 + nt * 16) * HH;
                    kb[2 * nt]     = *(const bf16x8*)kp;
                    kb[2 * nt + 1] = *(const bf16x8*)(kp + 32);
                }
            }
            // issue V loads for this step (consumed after softmax + P transpose)
            #pragma unroll
            for (int jj = 0; jj < 4; ++jj) {
                const ushort* vp = vbb + (size_t)(jj * 16) * TT + st * 64;
                vb[2 * jj]     = *(const bf16x8*)vp;
                vb[2 * jj + 1] = *(const bf16x8*)(vp + 32);
            }

            // causal mask (only the final s-tile crosses the diagonal)
            float p[4][4];
            float rm[4] = {-1e30f, -1e30f, -1e30f, -1e30f};
            if (st == ntile - 1) {
                #pragma unroll
                for (int nt = 0; nt < 4; ++nt) {
                    int s_abs = st * 64 + nt * 16 + l15;
                    #pragma unroll
                    for (int r = 0; r < 4; ++r) {
                        int t_abs = t0 + quad * 4 + r;
                        float v = (s_abs > t_abs) ? -1e30f : sf[nt][r];
                        p[nt][r] = v;
                        rm[r] = fmaxf(rm[r], v);
                    }
                }
            } else {
                #pragma unroll
                for (int nt = 0; nt < 4; ++nt)
                    #pragma unroll
                    for (int r = 0; r < 4; ++r) {
                        p[nt][r] = sf[nt][r];
                        rm[r] = fmaxf(rm[r], sf[nt][r]);
                    }
            }
            float alpha[4], rs[4] = {0.f, 0.f, 0.f, 0.f};
            #pragma unroll
            for (int r = 0; r < 4; ++r) {
                float v = rm[r];
                v = fmaxf(v, __shfl_xor(v, 1, 64));
                v = fmaxf(v, __shfl_xor(v, 2, 64));
                v = fmaxf(v, __shfl_xor(v, 4, 64));
                v = fmaxf(v, __shfl_xor(v, 8, 64));
                float mnew = fmaxf(mrun[r], v);
                alpha[r] = fexp2(mrun[r] - mnew);
                mrun[r] = mnew;
            }
            #pragma unroll
            for (int nt = 0; nt < 4; ++nt)
                #pragma unroll
                for (int r = 0; r < 4; ++r) {
                    float e = fexp2(p[nt][r] - mrun[r]);
                    p[nt][r] = e;
                    rs[r] += e;
                }
            #pragma unroll
            for (int r = 0; r < 4; ++r) {
                float v = rs[r];
                v += __shfl_xor(v, 1, 64);
                v += __shfl_xor(v, 2, 64);
                v += __shfl_xor(v, 4, 64);
                v += __shfl_xor(v, 8, 64);
                lrun[r] = lrun[r] * alpha[r] + v;
            }
            #pragma unroll
            for (int jj = 0; jj < 4; ++jj)
                #pragma unroll
                for (int r = 0; r < 4; ++r)
                    po[jj][r] *= alpha[r];

            // P: C-layout regs -> per-wave LDS -> A-layout frags (no barrier)
            #pragma unroll
            for (int nt = 0; nt < 4; ++nt)
                #pragma unroll
                for (int r = 0; r < 4; ++r)
                    Ps[w][(quad * 4 + r) * 72 + nt * 16 + l15] = f2bf(p[nt][r]);
            bf16x8 pa0 = *(const bf16x8*)&Ps[w][l15 * 72 + quad * 8];
            bf16x8 pa1 = *(const bf16x8*)&Ps[w][l15 * 72 + 32 + quad * 8];

            // O += P V (uses vb issued before softmax)
            #pragma unroll
            for (int jj = 0; jj < 4; ++jj) {
                po[jj] = __builtin_amdgcn_mfma_f32_16x16x32_bf16(pa0, vb[2 * jj], po[jj], 0, 0, 0);
                po[jj] = __builtin_amdgcn_mfma_f32_16x16x32_bf16(pa1, vb[2 * jj + 1], po[jj], 0, 0, 0);
            }
        }

        // write partials to LDS: unnormalized O + per-row m, l
        #pragma unroll
        for (int jj = 0; jj < 4; ++jj)
            #pragma unroll
            for (int r = 0; r < 4; ++r)
                Opart[w][(quad * 4 + r) * 64 + jj * 16 + l15] = po[jj][r];
        if (l15 == 0) {
            #pragma unroll
            for (int r = 0; r < 4; ++r) {
                mlm[w][quad * 4 + r] = mrun[r];
                mll[w][quad * 4 + r] = lrun[r];
            }
        }
    }

    __syncthreads();

    // ---- in-block merge: 1024 output elems by 256 threads ----
    #pragma unroll
    for (int j = 0; j < 4; ++j) {
        int e  = tid + j * 256;
        int rr = e >> 6, h = e & 63;
        float M = -1e30f;
        #pragma unroll
        for (int i = 0; i < NSPLIT; ++i) M = fmaxf(M, mlm[i][rr]);
        float L = 0.f, acc = 0.f;
        #pragma unroll
        for (int i = 0; i < NSPLIT; ++i) {
            float li = mll[i][rr];
            if (li > 0.f) {
                float wgt = fexp2(mlm[i][rr] - M);
                L   += wgt * li;
                acc += wgt * Opart[i][rr * 64 + h];
            }
        }
        out[(size_t)(b * TT + t0 + rr) * HH + h] = acc / L;
    }
}

// ---------------------------------------------------------------------------
extern "C" void kernel_launch(void* const* d_in, const int* in_sizes, int n_in,
                              void* d_out, int out_size, void* d_ws, size_t ws_size,
                              hipStream_t stream)
{
    const float* x  = (const float*)d_in[0];
    const float* Wq = (const float*)d_in[1];
    const float* Wk = (const float*)d_in[2];
    const float* Wv = (const float*)d_in[3];
    float* out = (float*)d_out;

    // ws layout: qg 1MB | kg 1MB | vtg 1MB | Wt 288KB
    ushort* qg  = (ushort*)d_ws;
    ushort* kg  = qg  + (size_t)BB * TT * HH;
    ushort* vtg = kg  + (size_t)BB * TT * HH;
    ushort* Wt  = vtg + (size_t)BB * TT * HH;

    prep_w    <<<dim3(12, 3),              dim3(256), 0, stream>>>(Wq, Wk, Wv, Wt);
    qkv_mfma  <<<dim3((BB * TT / 32) * 2), dim3(256), 0, stream>>>(x, Wt, qg, kg, vtg);
    attn_block<<<dim3(TT / 16, BB),        dim3(256), 0, stream>>>(qg, kg, vtg, out);
}